// Round 6
// baseline (2206.669 us; speedup 1.0000x reference)
//
#include <hip/hip_runtime.h>

#define N_LSTM 16
#define ISZ 128
#define HSZ 128
#define BSZ 32
#define TSZ 512
#define G4H 512
#define XROW (N_LSTM * ISZ)   // 2048
#define OROW (N_LSTM * HSZ)   // 2048

typedef __attribute__((ext_vector_type(8))) short s16x8;
typedef __attribute__((ext_vector_type(4))) float f32x4;

#define LOG2E 1.4426950408889634f

static __device__ __forceinline__ unsigned short f2bf(float f) {
    unsigned int u = __builtin_bit_cast(unsigned int, f);
    u += 0x7fffu + ((u >> 16) & 1u);
    return (unsigned short)(u >> 16);
}

// raw v_exp_f32: D = 2^x
static __device__ __forceinline__ float fexp2(float x) {
#if __has_builtin(__builtin_amdgcn_exp2f)
    return __builtin_amdgcn_exp2f(x);
#else
    return __expf(x * 0.6931471805599453f);
#endif
}

// lgkm-only barrier: syncs LDS producers/consumers WITHOUT draining vmcnt.
static __device__ __forceinline__ void barrier_lgkm() {
    __builtin_amdgcn_sched_barrier(0);
    asm volatile("s_waitcnt lgkmcnt(0)" ::: "memory");
    __builtin_amdgcn_s_barrier();
    __builtin_amdgcn_sched_barrier(0);
}

// ============================================================================
// XP pre-pass v2 (coalesced): xp[t][wg][wl][g][lane] = gsc[g]*(Wih.x + b)
// in the exact C-fragment layout the recurrent kernel consumes as MFMA C-in.
// float index: t*262144 + (wg*8+wl)*1024 + g*256 + ln*4,  wg = n*2+half.
// Each 512-thread block: (wg, 32 timesteps). x staged through LDS coalesced
// (each thread loads 4 consecutive floats of one row), then A-frags ds_read.
// Grid 32x16 = 512 blocks -> full chip.
// ============================================================================
__global__ __launch_bounds__(512, 2) void xp_gemm(
    const float* __restrict__ x, const float* __restrict__ Wih,
    const float* __restrict__ bih, const float* __restrict__ bhh,
    float* __restrict__ xp)
{
    __shared__ __align__(16) unsigned short xs[2][16][136];

    const int tid = threadIdx.x;
    const int wv  = tid >> 6;            // 0..7: col-chunk wave
    const int ln  = tid & 63;
    const int lm  = ln & 15;
    const int lq  = ln >> 4;
    const int wg  = blockIdx.x;          // 0..31 = n*2+half
    const int tc  = blockIdx.y;          // 0..15, 32 timesteps each
    const int n   = wg >> 1;
    const int b0  = (wg & 1) * 16;

    const float gsc[4] = {-LOG2E, -LOG2E, -2.f * LOG2E, -LOG2E};   // i,f,g,o
    s16x8 wih[4][4];
    f32x4 biasv[4];
    #pragma unroll
    for (int g = 0; g < 4; ++g) {
        const int col = g * 128 + wv * 16 + lm;
        const float s = gsc[g];
        const float bb = (bih[n * G4H + col] + bhh[n * G4H + col]) * s;
        biasv[g] = (f32x4){bb, bb, bb, bb};
        #pragma unroll
        for (int kt = 0; kt < 4; ++kt) {
            const float* pi = Wih + ((size_t)n * G4H + col) * ISZ + kt * 32 + lq * 8;
            s16x8 a;
            #pragma unroll
            for (int j = 0; j < 8; ++j) a[j] = (short)f2bf(pi[j] * s);
            wih[g][kt] = a;
        }
    }

    // coalesced x staging: thread -> (row sr, 4 floats at col sc)
    const int sr = tid >> 5;
    const int sc = (tid & 31) * 4;
    const float* xrow = x + (size_t)(b0 + sr) * TSZ * XROW + n * ISZ + sc;
    float* xpo = xp + (size_t)(wg * 8 + wv) * 1024 + ln * 4;

    float4 xr = *(const float4*)(xrow + (size_t)(tc * 32) * XROW);   // prefetch tt=0

    for (int tt = 0; tt < 32; ++tt) {
        const int t   = tc * 32 + tt;
        const int buf = tt & 1;
        {
            unsigned int lo = (unsigned int)f2bf(xr.x) | ((unsigned int)f2bf(xr.y) << 16);
            unsigned int hi = (unsigned int)f2bf(xr.z) | ((unsigned int)f2bf(xr.w) << 16);
            *(uint2*)&xs[buf][sr][sc] = make_uint2(lo, hi);
        }
        barrier_lgkm();
        if (tt + 1 < 32)
            xr = *(const float4*)(xrow + (size_t)(t + 1) * XROW);

        f32x4 acc[4];
        #pragma unroll
        for (int g = 0; g < 4; ++g) acc[g] = biasv[g];
        #pragma unroll
        for (int kt = 0; kt < 4; ++kt) {
            s16x8 axk = *(const s16x8*)&xs[buf][lm][kt * 32 + lq * 8];
            #pragma unroll
            for (int g = 0; g < 4; ++g)
                acc[g] = __builtin_amdgcn_mfma_f32_16x16x32_bf16(axk, wih[g][kt], acc[g], 0, 0, 0);
        }
        float* o = xpo + (size_t)t * 262144;
        #pragma unroll
        for (int g = 0; g < 4; ++g)
            *(f32x4*)(o + g * 256) = acc[g];
        // dbuf + the barrier in the NEXT iteration protects buf from WAR:
        // a wave passes that barrier only after its own lgkm (these ds_reads)
        // completed, so buf isn't rewritten until all reads of it are done.
    }
}

// ============================================================================
// Merged recurrent kernel: one WG per n (grid 16), 1024 threads = 16 waves
// (waves 0-7 -> batch rows 0-15, waves 8-15 -> rows 16-31; wave owns 16
// h-cols x 4 gates). 4 waves/SIMD doubles TLP to hide the barrier/LDS/chain
// latency that dominates the step. Per step: 16 h-MFMA with C-in = preloaded
// xp fragments (2-step-ahead register prefetch). Weights = whh only.
// ============================================================================
__global__ __launch_bounds__(1024, 4) void widelstm_rec_xp(
    const float* __restrict__ xp, const float* __restrict__ Whh,
    float* __restrict__ out)
{
    __shared__ __align__(16) unsigned short hbuf[2][32][136];

    const int tid = threadIdx.x;
    const int wv  = tid >> 6;        // 0..15
    const int wl  = wv & 7;          // col-chunk: h-units [16*wl, 16*wl+16)
    const int hf  = wv >> 3;         // batch half
    const int ln  = tid & 63;
    const int lm  = ln & 15;
    const int lq  = ln >> 4;
    const int n   = blockIdx.x;      // 0..15
    const int b0  = hf * 16;

    const float gsc[4] = {-LOG2E, -LOG2E, -2.f * LOG2E, -LOG2E};
    s16x8 whh[4][4];
    #pragma unroll
    for (int g = 0; g < 4; ++g) {
        const int col = g * 128 + wl * 16 + lm;
        const float s = gsc[g];
        #pragma unroll
        for (int kt = 0; kt < 4; ++kt) {
            const float* ph = Whh + ((size_t)n * G4H + col) * HSZ + kt * 32 + lq * 8;
            s16x8 b;
            #pragma unroll
            for (int j = 0; j < 8; ++j) b[j] = (short)f2bf(ph[j] * s);
            whh[g][kt] = b;
        }
    }

    // zero hbuf[0] (h(-1) = 0); visible after step-0's barrier
    for (int i = tid; i < 32 * 136; i += 1024)
        ((unsigned short*)hbuf[0])[i] = 0;

    // xp per-lane base; per-t stride 262144 floats (1 MiB)
    const float* xq = xp + (size_t)(((n * 2 + hf) * 8 + wl)) * 1024 + ln * 4;

    // prologue: preload xp(0), xp(1)
    f32x4 pA[4], pB[4];
    #pragma unroll
    for (int g = 0; g < 4; ++g) pA[g] = *(const f32x4*)(xq + g * 256);
    #pragma unroll
    for (int g = 0; g < 4; ++g) pB[g] = *(const f32x4*)(xq + 262144 + g * 256);

    float cprev[4] = {0.f, 0.f, 0.f, 0.f};
    float hlast[4] = {0.f, 0.f, 0.f, 0.f};
    const int ocol = n * HSZ + wl * 16 + lm;

    float* po0 = out + (size_t)(b0 + lq * 4 + 0) * TSZ * OROW + ocol;
    float* po1 = out + (size_t)(b0 + lq * 4 + 1) * TSZ * OROW + ocol;
    float* po2 = out + (size_t)(b0 + lq * 4 + 2) * TSZ * OROW + ocol;
    float* po3 = out + (size_t)(b0 + lq * 4 + 3) * TSZ * OROW + ocol;

#define XP_STEP(T_, CUR_, NXT_, PC_)                                                        \
    {                                                                                       \
        const int t_ = (T_);                                                                \
        barrier_lgkm();  /* h(t-1) writes now visible */                                    \
        s16x8 ah0 = *(const s16x8*)&hbuf[CUR_][b0 + lm][0 * 32 + lq * 8];                   \
        s16x8 ah1 = *(const s16x8*)&hbuf[CUR_][b0 + lm][1 * 32 + lq * 8];                   \
        s16x8 ah2 = *(const s16x8*)&hbuf[CUR_][b0 + lm][2 * 32 + lq * 8];                   \
        s16x8 ah3 = *(const s16x8*)&hbuf[CUR_][b0 + lm][3 * 32 + lq * 8];                   \
        f32x4 hacc[4];                                                                      \
        _Pragma("unroll")                                                                   \
        for (int g = 0; g < 4; ++g)                                                         \
            hacc[g] = __builtin_amdgcn_mfma_f32_16x16x32_bf16(ah0, whh[g][0], PC_[g], 0, 0, 0); \
        _Pragma("unroll")                                                                   \
        for (int g = 0; g < 4; ++g)                                                         \
            hacc[g] = __builtin_amdgcn_mfma_f32_16x16x32_bf16(ah1, whh[g][1], hacc[g], 0, 0, 0); \
        _Pragma("unroll")                                                                   \
        for (int g = 0; g < 4; ++g)                                                         \
            hacc[g] = __builtin_amdgcn_mfma_f32_16x16x32_bf16(ah2, whh[g][2], hacc[g], 0, 0, 0); \
        _Pragma("unroll")                                                                   \
        for (int g = 0; g < 4; ++g)                                                         \
            hacc[g] = __builtin_amdgcn_mfma_f32_16x16x32_bf16(ah3, whh[g][3], hacc[g], 0, 0, 0); \
        if (t_ + 2 < TSZ) { /* prefetch xp(t+2) into the just-consumed regs */              \
            const float* p = xq + (size_t)(t_ + 2) * 262144;                                \
            _Pragma("unroll")                                                               \
            for (int g = 0; g < 4; ++g) PC_[g] = *(const f32x4*)(p + g * 256);              \
        }                                                                                   \
        _Pragma("unroll")                                                                   \
        for (int r = 0; r < 4; ++r) {                                                       \
            float ei = fexp2(hacc[0][r]);                                                   \
            float ef = fexp2(hacc[1][r]);                                                   \
            float eg = fexp2(fminf(hacc[2][r], 80.f));                                      \
            float eo = fexp2(hacc[3][r]);                                                   \
            float fv = __builtin_amdgcn_rcpf(1.f + ef);                                     \
            float ig = (1.f - eg) * __builtin_amdgcn_rcpf((1.f + ei) * (1.f + eg));         \
            float c  = fv * cprev[r] + ig;                                                  \
            cprev[r] = c;                                                                   \
            float ec = fexp2(fminf(c * (-2.f * LOG2E), 80.f));                              \
            float hv = (1.f - ec) * __builtin_amdgcn_rcpf((1.f + eo) * (1.f + ec));         \
            hlast[r] = hv;                                                                  \
            hbuf[NXT_][b0 + lq * 4 + r][wl * 16 + lm] = f2bf(hv);                           \
            if (r == 0) { *po0 = hv; po0 += OROW; }                                         \
            if (r == 1) { *po1 = hv; po1 += OROW; }                                         \
            if (r == 2) { *po2 = hv; po2 += OROW; }                                         \
            if (r == 3) { *po3 = hv; po3 += OROW; }                                         \
        }                                                                                   \
    }

    for (int t = 0; t < TSZ; t += 2) {
        XP_STEP(t, 0, 1, pA);
        XP_STEP(t + 1, 1, 0, pB);
    }
#undef XP_STEP

    const size_t hn_off = (size_t)BSZ * TSZ * OROW;
    const size_t cn_off = hn_off + (size_t)BSZ * OROW;
    #pragma unroll
    for (int r = 0; r < 4; ++r) {
        const int row = lq * 4 + r;
        const size_t idx = (size_t)(b0 + row) * OROW + ocol;
        out[hn_off + idx] = hlast[r];
        out[cn_off + idx] = cprev[r];
    }
}

// ============================================================================
// Fallback path (R3 structure), unchanged: x as pre-packed A-fragments
// (64 MiB ws) or fully-fused staging (no ws).
// ============================================================================
__global__ void x_to_frag(const float* __restrict__ x, int4* __restrict__ xf) {
    const unsigned G = blockIdx.x * 256 + threadIdx.x;   // < 4194304
    const int ln = G & 63;
    const int kt = (G >> 6) & 3;
    const int wg = (G >> 8) & 31;
    const int t  = G >> 13;
    const int lm = ln & 15, lq = ln >> 4;
    const int n  = wg >> 1;
    const int b0 = (wg & 1) * 16;
    const float* src = x + (size_t)(b0 + lm) * (TSZ * XROW) + (size_t)t * XROW
                         + n * ISZ + kt * 32 + lq * 8;
    float4 a = *(const float4*)src;
    float4 b = *(const float4*)(src + 4);
    s16x8 f;
    f[0] = (short)f2bf(a.x); f[1] = (short)f2bf(a.y);
    f[2] = (short)f2bf(a.z); f[3] = (short)f2bf(a.w);
    f[4] = (short)f2bf(b.x); f[5] = (short)f2bf(b.y);
    f[6] = (short)f2bf(b.z); f[7] = (short)f2bf(b.w);
    xf[G] = __builtin_bit_cast(int4, f);
}

template <int PRE>
__global__ __launch_bounds__(512, 2) void widelstm_fused(
    const float* __restrict__ x, const int4* __restrict__ xf,
    const float* __restrict__ Wih, const float* __restrict__ Whh,
    const float* __restrict__ bih, const float* __restrict__ bhh,
    float* __restrict__ out)
{
    __shared__ __align__(16) unsigned short xbuf[2][16][136];   // PRE=0 only
    __shared__ __align__(16) unsigned short hbuf[2][16][136];

    const int tid = threadIdx.x;
    const int wv  = tid >> 6;
    const int ln  = tid & 63;
    const int lm  = ln & 15;
    const int lq  = ln >> 4;
    const int n    = blockIdx.x >> 1;
    const int half = blockIdx.x & 1;
    const int b0   = half * 16;

    const float gsc[4] = {-LOG2E, -LOG2E, -2.f * LOG2E, -LOG2E};
    s16x8 wih[4][4], whh[4][4];
    f32x4 biasv[4];
    #pragma unroll
    for (int g = 0; g < 4; ++g) {
        const int col = g * 128 + wv * 16 + lm;
        const float s = gsc[g];
        const float bb = (bih[n * G4H + col] + bhh[n * G4H + col]) * s;
        biasv[g] = (f32x4){bb, bb, bb, bb};
        #pragma unroll
        for (int kt = 0; kt < 4; ++kt) {
            const float* pi = Wih + ((size_t)n * G4H + col) * ISZ + kt * 32 + lq * 8;
            const float* ph = Whh + ((size_t)n * G4H + col) * HSZ + kt * 32 + lq * 8;
            s16x8 a, b;
            #pragma unroll
            for (int j = 0; j < 8; ++j) {
                a[j] = (short)f2bf(pi[j] * s);
                b[j] = (short)f2bf(ph[j] * s);
            }
            wih[g][kt] = a;
            whh[g][kt] = b;
        }
    }

    for (int i = tid; i < 16 * 136; i += 512)
        ((unsigned short*)hbuf[0])[i] = 0;

    const int sr = tid >> 5;
    const int sc = (tid & 31) * 4;
    const float* xrow = x + (size_t)(b0 + sr) * TSZ * XROW + n * ISZ + sc;
    const int4* xfb = xf + (size_t)blockIdx.x * 256 + ln;

    float4 xr;
    s16x8 xra, xrb, xrc, xrd;
    f32x4 xacc[4];

    if constexpr (PRE) {
        s16x8 c0 = __builtin_bit_cast(s16x8, xfb[0]);
        s16x8 c1 = __builtin_bit_cast(s16x8, xfb[64]);
        s16x8 c2 = __builtin_bit_cast(s16x8, xfb[128]);
        s16x8 c3 = __builtin_bit_cast(s16x8, xfb[192]);
        #pragma unroll
        for (int g = 0; g < 4; ++g)
            xacc[g] = __builtin_amdgcn_mfma_f32_16x16x32_bf16(c0, wih[g][0], biasv[g], 0, 0, 0);
        #pragma unroll
        for (int g = 0; g < 4; ++g)
            xacc[g] = __builtin_amdgcn_mfma_f32_16x16x32_bf16(c1, wih[g][1], xacc[g], 0, 0, 0);
        #pragma unroll
        for (int g = 0; g < 4; ++g)
            xacc[g] = __builtin_amdgcn_mfma_f32_16x16x32_bf16(c2, wih[g][2], xacc[g], 0, 0, 0);
        #pragma unroll
        for (int g = 0; g < 4; ++g)
            xacc[g] = __builtin_amdgcn_mfma_f32_16x16x32_bf16(c3, wih[g][3], xacc[g], 0, 0, 0);
        xra = __builtin_bit_cast(s16x8, xfb[8192]);
        xrb = __builtin_bit_cast(s16x8, xfb[8192 + 64]);
        xrc = __builtin_bit_cast(s16x8, xfb[8192 + 128]);
        xrd = __builtin_bit_cast(s16x8, xfb[8192 + 192]);
    } else {
        xr = *(const float4*)(xrow);
        unsigned int lo = (unsigned int)f2bf(xr.x) | ((unsigned int)f2bf(xr.y) << 16);
        unsigned int hi = (unsigned int)f2bf(xr.z) | ((unsigned int)f2bf(xr.w) << 16);
        *(uint2*)&xbuf[0][sr][sc] = make_uint2(lo, hi);
        barrier_lgkm();
        #pragma unroll
        for (int kt = 0; kt < 4; ++kt) {
            s16x8 axk = *(const s16x8*)&xbuf[0][lm][kt * 32 + lq * 8];
            #pragma unroll
            for (int g = 0; g < 4; ++g)
                xacc[g] = __builtin_amdgcn_mfma_f32_16x16x32_bf16(
                    axk, wih[g][kt], kt == 0 ? biasv[g] : xacc[g], 0, 0, 0);
        }
        xr = *(const float4*)(xrow + (size_t)XROW);
    }

    float cprev[4] = {0.f, 0.f, 0.f, 0.f};
    float hlast[4] = {0.f, 0.f, 0.f, 0.f};
    const int ocol = n * HSZ + wv * 16 + lm;

    float* po0 = out + (size_t)(b0 + lq * 4 + 0) * TSZ * OROW + ocol;
    float* po1 = out + (size_t)(b0 + lq * 4 + 1) * TSZ * OROW + ocol;
    float* po2 = out + (size_t)(b0 + lq * 4 + 2) * TSZ * OROW + ocol;
    float* po3 = out + (size_t)(b0 + lq * 4 + 3) * TSZ * OROW + ocol;

#define LSTM_STEP(T_, CUR_, NXT_)                                                           \
    {                                                                                       \
        const int t_ = (T_);                                                                \
        if constexpr (!PRE) {                                                               \
            if (t_ + 1 < TSZ) {                                                             \
                unsigned int lo = (unsigned int)f2bf(xr.x) | ((unsigned int)f2bf(xr.y) << 16); \
                unsigned int hi = (unsigned int)f2bf(xr.z) | ((unsigned int)f2bf(xr.w) << 16); \
                *(uint2*)&xbuf[NXT_][sr][sc] = make_uint2(lo, hi);                          \
            }                                                                               \
        }                                                                                   \
        barrier_lgkm();                                                                     \
        s16x8 ah0 = *(const s16x8*)&hbuf[CUR_][lm][0 * 32 + lq * 8];                        \
        s16x8 ah1 = *(const s16x8*)&hbuf[CUR_][lm][1 * 32 + lq * 8];                        \
        s16x8 ah2 = *(const s16x8*)&hbuf[CUR_][lm][2 * 32 + lq * 8];                        \
        s16x8 ah3 = *(const s16x8*)&hbuf[CUR_][lm][3 * 32 + lq * 8];                        \
        if constexpr (!PRE) {                                                               \
            if (t_ + 2 < TSZ) xr = *(const float4*)(xrow + (size_t)(t_ + 2) * XROW);        \
        }                                                                                   \
        f32x4 hacc[4];                                                                      \
        _Pragma("unroll")                                                                   \
        for (int g = 0; g < 4; ++g)                                                         \
            hacc[g] = __builtin_amdgcn_mfma_f32_16x16x32_bf16(ah0, whh[g][0], xacc[g], 0, 0, 0); \
        _Pragma("unroll")                                                                   \
        for (int g = 0; g < 4; ++g)                                                         \
            hacc[g] = __builtin_amdgcn_mfma_f32_16x16x32_bf16(ah1, whh[g][1], hacc[g], 0, 0, 0); \
        _Pragma("unroll")                                                                   \
        for (int g = 0; g < 4; ++g)                                                         \
            hacc[g] = __builtin_amdgcn_mfma_f32_16x16x32_bf16(ah2, whh[g][2], hacc[g], 0, 0, 0); \
        _Pragma("unroll")                                                                   \
        for (int g = 0; g < 4; ++g)                                                         \
            hacc[g] = __builtin_amdgcn_mfma_f32_16x16x32_bf16(ah3, whh[g][3], hacc[g], 0, 0, 0); \
        if (t_ + 1 < TSZ) {                                                                 \
            if constexpr (PRE) {                                                            \
                _Pragma("unroll")                                                           \
                for (int g = 0; g < 4; ++g)                                                 \
                    xacc[g] = __builtin_amdgcn_mfma_f32_16x16x32_bf16(xra, wih[g][0], biasv[g], 0, 0, 0); \
                _Pragma("unroll")                                                           \
                for (int g = 0; g < 4; ++g)                                                 \
                    xacc[g] = __builtin_amdgcn_mfma_f32_16x16x32_bf16(xrb, wih[g][1], xacc[g], 0, 0, 0); \
                _Pragma("unroll")                                                           \
                for (int g = 0; g < 4; ++g)                                                 \
                    xacc[g] = __builtin_amdgcn_mfma_f32_16x16x32_bf16(xrc, wih[g][2], xacc[g], 0, 0, 0); \
                _Pragma("unroll")                                                           \
                for (int g = 0; g < 4; ++g)                                                 \
                    xacc[g] = __builtin_amdgcn_mfma_f32_16x16x32_bf16(xrd, wih[g][3], xacc[g], 0, 0, 0); \
                if (t_ + 2 < TSZ) {                                                         \
                    const int4* p = xfb + (size_t)(t_ + 2) * 8192;                          \
                    xra = __builtin_bit_cast(s16x8, p[0]);                                  \
                    xrb = __builtin_bit_cast(s16x8, p[64]);                                 \
                    xrc = __builtin_bit_cast(s16x8, p[128]);                                \
                    xrd = __builtin_bit_cast(s16x8, p[192]);                                \
                }                                                                           \
            } else {                                                                        \
                _Pragma("unroll")                                                           \
                for (int kt = 0; kt < 4; ++kt) {                                            \
                    s16x8 axk = *(const s16x8*)&xbuf[NXT_][lm][kt * 32 + lq * 8];           \
                    _Pragma("unroll")                                                       \
                    for (int g = 0; g < 4; ++g)                                             \
                        xacc[g] = __builtin_amdgcn_mfma_f32_16x16x32_bf16(                  \
                            axk, wih[g][kt], kt == 0 ? biasv[g] : xacc[g], 0, 0, 0);        \
                }                                                                           \
            }                                                                               \
        }                                                                                   \
        _Pragma("unroll")                                                                   \
        for (int r = 0; r < 4; ++r) {                                                       \
            float ei = fexp2(hacc[0][r]);                                                   \
            float ef = fexp2(hacc[1][r]);                                                   \
            float eg = fexp2(fminf(hacc[2][r], 80.f));                                      \
            float eo = fexp2(hacc[3][r]);                                                   \
            float fv = __builtin_amdgcn_rcpf(1.f + ef);                                     \
            float ig = (1.f - eg) * __builtin_amdgcn_rcpf((1.f + ei) * (1.f + eg));         \
            float c  = fv * cprev[r] + ig;                                                  \
            cprev[r] = c;                                                                   \
            float ec = fexp2(fminf(c * (-2.f * LOG2E), 80.f));                              \
            float hv = (1.f - ec) * __builtin_amdgcn_rcpf((1.f + eo) * (1.f + ec));         \
            hlast[r] = hv;                                                                  \
            hbuf[NXT_][lq * 4 + r][wv * 16 + lm] = f2bf(hv);                                \
            if (r == 0) { *po0 = hv; po0 += OROW; }                                         \
            if (r == 1) { *po1 = hv; po1 += OROW; }                                         \
            if (r == 2) { *po2 = hv; po2 += OROW; }                                         \
            if (r == 3) { *po3 = hv; po3 += OROW; }                                         \
        }                                                                                   \
    }

    for (int t = 0; t < TSZ; t += 2) {
        LSTM_STEP(t, 0, 1);
        LSTM_STEP(t + 1, 1, 0);
    }
#undef LSTM_STEP

    const size_t hn_off = (size_t)BSZ * TSZ * OROW;
    const size_t cn_off = hn_off + (size_t)BSZ * OROW;
    #pragma unroll
    for (int r = 0; r < 4; ++r) {
        const int row = lq * 4 + r;
        const size_t idx = (size_t)(b0 + row) * OROW + ocol;
        out[hn_off + idx] = hlast[r];
        out[cn_off + idx] = cprev[r];
    }
}

extern "C" void kernel_launch(void* const* d_in, const int* in_sizes, int n_in,
                              void* d_out, int out_size, void* d_ws, size_t ws_size,
                              hipStream_t stream) {
    const float* x   = (const float*)d_in[0];
    const float* Wih = (const float*)d_in[1];
    const float* Whh = (const float*)d_in[2];
    const float* bih = (const float*)d_in[3];
    const float* bhh = (const float*)d_in[4];
    float* out = (float*)d_out;

    const size_t needXP = (size_t)TSZ * 32 * 8 * 4 * 256 * 4;   // 512 MiB
    const size_t needFR = (size_t)TSZ * 32 * 4 * 64 * 16;       // 64 MiB
    if (d_ws != nullptr && ws_size >= needXP) {
        float* xp = (float*)d_ws;
        xp_gemm<<<dim3(32, 16), dim3(512), 0, stream>>>(x, Wih, bih, bhh, xp);
        widelstm_rec_xp<<<dim3(16), dim3(1024), 0, stream>>>(xp, Whh, out);
    } else if (d_ws != nullptr && ws_size >= needFR) {
        int4* xfrag = (int4*)d_ws;
        x_to_frag<<<dim3(16384), dim3(256), 0, stream>>>(x, xfrag);
        widelstm_fused<1><<<dim3(32), dim3(512), 0, stream>>>(x, xfrag, Wih, Whh, bih, bhh, out);
    } else {
        widelstm_fused<0><<<dim3(32), dim3(512), 0, stream>>>(x, nullptr, Wih, Whh, bih, bhh, out);
    }
}

// Round 7
// 726.602 us; speedup vs baseline: 3.0370x; 3.0370x over previous
//
#include <hip/hip_runtime.h>

#define N_LSTM 16
#define ISZ 128
#define HSZ 128
#define BSZ 32
#define TSZ 512
#define G4H 512
#define XROW (N_LSTM * ISZ)   // 2048
#define OROW (N_LSTM * HSZ)   // 2048

typedef __attribute__((ext_vector_type(8))) short s16x8;
typedef __attribute__((ext_vector_type(4))) float f32x4;

#define LOG2E 1.4426950408889634f

static __device__ __forceinline__ unsigned short f2bf(float f) {
    unsigned int u = __builtin_bit_cast(unsigned int, f);
    u += 0x7fffu + ((u >> 16) & 1u);
    return (unsigned short)(u >> 16);
}

// raw v_exp_f32: D = 2^x
static __device__ __forceinline__ float fexp2(float x) {
#if __has_builtin(__builtin_amdgcn_exp2f)
    return __builtin_amdgcn_exp2f(x);
#else
    return __expf(x * 0.6931471805599453f);
#endif
}

// lgkm-only barrier: syncs LDS producers/consumers WITHOUT draining vmcnt,
// so global stores / prefetch loads stay in flight across the per-step barrier.
static __device__ __forceinline__ void barrier_lgkm() {
    __builtin_amdgcn_sched_barrier(0);
    asm volatile("s_waitcnt lgkmcnt(0)" ::: "memory");
    __builtin_amdgcn_s_barrier();
    __builtin_amdgcn_sched_barrier(0);
}

// Pre-pass: emit x as bf16 MFMA A-FRAGMENTS in the exact order the recurrent
// kernel consumes: frag id G = t*8192 + wg*256 + kt*64 + ln (16 B each).
__global__ void x_to_frag(const float* __restrict__ x, int4* __restrict__ xf) {
    const unsigned G = blockIdx.x * 256 + threadIdx.x;   // < 4194304
    const int ln = G & 63;
    const int kt = (G >> 6) & 3;
    const int wg = (G >> 8) & 31;
    const int t  = G >> 13;
    const int lm = ln & 15, lq = ln >> 4;
    const int n  = wg >> 1;
    const int b0 = (wg & 1) * 16;
    const float* src = x + (size_t)(b0 + lm) * (TSZ * XROW) + (size_t)t * XROW
                         + n * ISZ + kt * 32 + lq * 8;
    float4 a = *(const float4*)src;
    float4 b = *(const float4*)(src + 4);
    s16x8 f;
    f[0] = (short)f2bf(a.x); f[1] = (short)f2bf(a.y);
    f[2] = (short)f2bf(a.z); f[3] = (short)f2bf(a.w);
    f[4] = (short)f2bf(b.x); f[5] = (short)f2bf(b.y);
    f[6] = (short)f2bf(b.z); f[7] = (short)f2bf(b.w);
    xf[G] = __builtin_bit_cast(int4, f);
}

// One workgroup = (n, batch-half of 16). 8 waves; wave w owns hidden units
// [16w,16w+16) x all 4 gates. Weights PRESCALED by -log2e (i,f,o) / -2log2e (g)
// so gate pre-activations are exp2-ready. h round-trips through LDS bf16.
// x arrives as pre-packed A-fragments from global (PRE=1), prefetched 1 ahead.
// launch_bounds (512, 1): 1 block/CU -> 256-VGPR cap (the (512,2) used through
// R3 capped at 128 and forced AGPR banking of the 128-VGPR weight set).
// Dual xacc (A/B): the x-projection MFMAs for t+1 issue right after the
// barrier, filling the ds_read latency window, without clobbering this step's
// C-in.
template <int PRE>
__global__ __launch_bounds__(512, 1) void widelstm_fused(
    const float* __restrict__ x, const int4* __restrict__ xf,
    const float* __restrict__ Wih, const float* __restrict__ Whh,
    const float* __restrict__ bih, const float* __restrict__ bhh,
    float* __restrict__ out)
{
    __shared__ __align__(16) unsigned short xbuf[2][16][136];   // PRE=0 only
    __shared__ __align__(16) unsigned short hbuf[2][16][136];

    const int tid = threadIdx.x;
    const int wv  = tid >> 6;
    const int ln  = tid & 63;
    const int lm  = ln & 15;
    const int lq  = ln >> 4;
    const int n    = blockIdx.x >> 1;
    const int half = blockIdx.x & 1;
    const int b0   = half * 16;

    const float gsc[4] = {-LOG2E, -LOG2E, -2.f * LOG2E, -LOG2E};   // i,f,g,o
    s16x8 wih[4][4], whh[4][4];
    f32x4 biasv[4];
    #pragma unroll
    for (int g = 0; g < 4; ++g) {
        const int col = g * 128 + wv * 16 + lm;
        const float s = gsc[g];
        const float bb = (bih[n * G4H + col] + bhh[n * G4H + col]) * s;
        biasv[g] = (f32x4){bb, bb, bb, bb};
        #pragma unroll
        for (int kt = 0; kt < 4; ++kt) {
            const float* pi = Wih + ((size_t)n * G4H + col) * ISZ + kt * 32 + lq * 8;
            const float* ph = Whh + ((size_t)n * G4H + col) * HSZ + kt * 32 + lq * 8;
            s16x8 a, b;
            #pragma unroll
            for (int j = 0; j < 8; ++j) {
                a[j] = (short)f2bf(pi[j] * s);
                b[j] = (short)f2bf(ph[j] * s);
            }
            wih[g][kt] = a;
            whh[g][kt] = b;
        }
    }

    // zero hbuf[0] (h(-1) = 0); visible after step-0's barrier
    for (int i = tid; i < 16 * 136; i += 512)
        ((unsigned short*)hbuf[0])[i] = 0;

    const int sr = tid >> 5;
    const int sc = (tid & 31) * 4;
    const float* xrow = x + (size_t)(b0 + sr) * TSZ * XROW + n * ISZ + sc;   // PRE=0
    const int4* xfb = xf + (size_t)blockIdx.x * 256 + ln;                    // PRE=1

    float4 xr;                   // PRE=0 prefetch
    s16x8 xra, xrb, xrc, xrd;    // PRE=1 prefetched frags (for t+1)
    f32x4 xaccA[4], xaccB[4];    // double-buffered x-projection accumulators

    // ---- prologue: xaccA = bias + Wih*x(0); prefetch frags for x(1)
    if constexpr (PRE) {
        s16x8 c0 = __builtin_bit_cast(s16x8, xfb[0]);
        s16x8 c1 = __builtin_bit_cast(s16x8, xfb[64]);
        s16x8 c2 = __builtin_bit_cast(s16x8, xfb[128]);
        s16x8 c3 = __builtin_bit_cast(s16x8, xfb[192]);
        #pragma unroll
        for (int g = 0; g < 4; ++g)
            xaccA[g] = __builtin_amdgcn_mfma_f32_16x16x32_bf16(c0, wih[g][0], biasv[g], 0, 0, 0);
        #pragma unroll
        for (int g = 0; g < 4; ++g)
            xaccA[g] = __builtin_amdgcn_mfma_f32_16x16x32_bf16(c1, wih[g][1], xaccA[g], 0, 0, 0);
        #pragma unroll
        for (int g = 0; g < 4; ++g)
            xaccA[g] = __builtin_amdgcn_mfma_f32_16x16x32_bf16(c2, wih[g][2], xaccA[g], 0, 0, 0);
        #pragma unroll
        for (int g = 0; g < 4; ++g)
            xaccA[g] = __builtin_amdgcn_mfma_f32_16x16x32_bf16(c3, wih[g][3], xaccA[g], 0, 0, 0);
        xra = __builtin_bit_cast(s16x8, xfb[8192]);
        xrb = __builtin_bit_cast(s16x8, xfb[8192 + 64]);
        xrc = __builtin_bit_cast(s16x8, xfb[8192 + 128]);
        xrd = __builtin_bit_cast(s16x8, xfb[8192 + 192]);
    } else {
        xr = *(const float4*)(xrow);
        unsigned int lo = (unsigned int)f2bf(xr.x) | ((unsigned int)f2bf(xr.y) << 16);
        unsigned int hi = (unsigned int)f2bf(xr.z) | ((unsigned int)f2bf(xr.w) << 16);
        *(uint2*)&xbuf[0][sr][sc] = make_uint2(lo, hi);
        barrier_lgkm();
        #pragma unroll
        for (int kt = 0; kt < 4; ++kt) {
            s16x8 axk = *(const s16x8*)&xbuf[0][lm][kt * 32 + lq * 8];
            #pragma unroll
            for (int g = 0; g < 4; ++g)
                xaccA[g] = __builtin_amdgcn_mfma_f32_16x16x32_bf16(
                    axk, wih[g][kt], kt == 0 ? biasv[g] : xaccA[g], 0, 0, 0);
        }
        xr = *(const float4*)(xrow + (size_t)XROW);
    }

    float cprev[4] = {0.f, 0.f, 0.f, 0.f};
    float hlast[4] = {0.f, 0.f, 0.f, 0.f};
    const int ocol = n * HSZ + wv * 16 + lm;

    float* po0 = out + (size_t)(b0 + lq * 4 + 0) * TSZ * OROW + ocol;
    float* po1 = out + (size_t)(b0 + lq * 4 + 1) * TSZ * OROW + ocol;
    float* po2 = out + (size_t)(b0 + lq * 4 + 2) * TSZ * OROW + ocol;
    float* po3 = out + (size_t)(b0 + lq * 4 + 3) * TSZ * OROW + ocol;

    // epilogue: 5 exp2 + 2 rcp per element (common-denominator c-update):
    // c = [cp*(1+ei)(1+eg) + (1-eg)(1+ef)] / [(1+ef)(1+ei)(1+eg)]
    // h = (1-ec) / [(1+eo)(1+ec)]
#define PH_EPI(NXT_)                                                                        \
    _Pragma("unroll")                                                                       \
    for (int r = 0; r < 4; ++r) {                                                           \
        float ei = fexp2(hacc[0][r]);                                                       \
        float ef = fexp2(hacc[1][r]);                                                       \
        float eg = fexp2(fminf(hacc[2][r], 80.f));                                          \
        float eo = fexp2(hacc[3][r]);                                                       \
        float af = 1.f + ef;                                                                \
        float p1 = (1.f + ei) * (1.f + eg);                                                 \
        float num = cprev[r] * p1 + (1.f - eg) * af;                                        \
        float c   = num * __builtin_amdgcn_rcpf(af * p1);                                   \
        cprev[r] = c;                                                                       \
        float ec = fexp2(fminf(c * (-2.f * LOG2E), 80.f));                                  \
        float hv = (1.f - ec) * __builtin_amdgcn_rcpf((1.f + eo) * (1.f + ec));             \
        hlast[r] = hv;                                                                      \
        hbuf[NXT_][lq * 4 + r][wv * 16 + lm] = f2bf(hv);                                    \
        if (r == 0) { *po0 = hv; po0 += OROW; }                                             \
        if (r == 1) { *po1 = hv; po1 += OROW; }                                             \
        if (r == 2) { *po2 = hv; po2 += OROW; }                                             \
        if (r == 3) { *po3 = hv; po3 += OROW; }                                             \
    }

    if constexpr (PRE) {
        // Step t: XC_ holds bias+Wih*x(t) (C-in); PH_X fills XN_ for t+1 while
        // the ds_reads of h(t-1) are in flight (x-MFMAs have no LDS dep).
#define STEP_P(T_, CUR_, NXT_, XC_, XN_)                                                    \
    {                                                                                       \
        const int t_ = (T_);                                                                \
        barrier_lgkm();  /* h(t-1) writes now visible */                                    \
        s16x8 ah0 = *(const s16x8*)&hbuf[CUR_][lm][0 * 32 + lq * 8];                        \
        s16x8 ah1 = *(const s16x8*)&hbuf[CUR_][lm][1 * 32 + lq * 8];                        \
        s16x8 ah2 = *(const s16x8*)&hbuf[CUR_][lm][2 * 32 + lq * 8];                        \
        s16x8 ah3 = *(const s16x8*)&hbuf[CUR_][lm][3 * 32 + lq * 8];                        \
        if (t_ + 1 < TSZ) { /* x-projection for t+1, overlapping ds latency */              \
            _Pragma("unroll")                                                               \
            for (int g = 0; g < 4; ++g)                                                     \
                XN_[g] = __builtin_amdgcn_mfma_f32_16x16x32_bf16(xra, wih[g][0], biasv[g], 0, 0, 0); \
            _Pragma("unroll")                                                               \
            for (int g = 0; g < 4; ++g)                                                     \
                XN_[g] = __builtin_amdgcn_mfma_f32_16x16x32_bf16(xrb, wih[g][1], XN_[g], 0, 0, 0); \
            _Pragma("unroll")                                                               \
            for (int g = 0; g < 4; ++g)                                                     \
                XN_[g] = __builtin_amdgcn_mfma_f32_16x16x32_bf16(xrc, wih[g][2], XN_[g], 0, 0, 0); \
            _Pragma("unroll")                                                               \
            for (int g = 0; g < 4; ++g)                                                     \
                XN_[g] = __builtin_amdgcn_mfma_f32_16x16x32_bf16(xrd, wih[g][3], XN_[g], 0, 0, 0); \
            if (t_ + 2 < TSZ) { /* prefetch frags for t+2 */                                \
                const int4* p = xfb + (size_t)(t_ + 2) * 8192;                              \
                xra = __builtin_bit_cast(s16x8, p[0]);                                      \
                xrb = __builtin_bit_cast(s16x8, p[64]);                                     \
                xrc = __builtin_bit_cast(s16x8, p[128]);                                    \
                xrd = __builtin_bit_cast(s16x8, p[192]);                                    \
            }                                                                               \
        }                                                                                   \
        f32x4 hacc[4];                                                                      \
        _Pragma("unroll")                                                                   \
        for (int g = 0; g < 4; ++g)                                                         \
            hacc[g] = __builtin_amdgcn_mfma_f32_16x16x32_bf16(ah0, whh[g][0], XC_[g], 0, 0, 0); \
        _Pragma("unroll")                                                                   \
        for (int g = 0; g < 4; ++g)                                                         \
            hacc[g] = __builtin_amdgcn_mfma_f32_16x16x32_bf16(ah1, whh[g][1], hacc[g], 0, 0, 0); \
        _Pragma("unroll")                                                                   \
        for (int g = 0; g < 4; ++g)                                                         \
            hacc[g] = __builtin_amdgcn_mfma_f32_16x16x32_bf16(ah2, whh[g][2], hacc[g], 0, 0, 0); \
        _Pragma("unroll")                                                                   \
        for (int g = 0; g < 4; ++g)                                                         \
            hacc[g] = __builtin_amdgcn_mfma_f32_16x16x32_bf16(ah3, whh[g][3], hacc[g], 0, 0, 0); \
        PH_EPI(NXT_);                                                                       \
    }

        for (int t = 0; t < TSZ; t += 2) {
            STEP_P(t, 0, 1, xaccA, xaccB);
            STEP_P(t + 1, 1, 0, xaccB, xaccA);
        }
#undef STEP_P
    } else {
        // Fallback: in-kernel staging, single xacc (xaccA), original order.
#define STEP_0(T_, CUR_, NXT_)                                                              \
    {                                                                                       \
        const int t_ = (T_);                                                                \
        if (t_ + 1 < TSZ) {                                                                 \
            unsigned int lo = (unsigned int)f2bf(xr.x) | ((unsigned int)f2bf(xr.y) << 16);  \
            unsigned int hi = (unsigned int)f2bf(xr.z) | ((unsigned int)f2bf(xr.w) << 16);  \
            *(uint2*)&xbuf[NXT_][sr][sc] = make_uint2(lo, hi);                              \
        }                                                                                   \
        barrier_lgkm();                                                                     \
        s16x8 ah0 = *(const s16x8*)&hbuf[CUR_][lm][0 * 32 + lq * 8];                        \
        s16x8 ah1 = *(const s16x8*)&hbuf[CUR_][lm][1 * 32 + lq * 8];                        \
        s16x8 ah2 = *(const s16x8*)&hbuf[CUR_][lm][2 * 32 + lq * 8];                        \
        s16x8 ah3 = *(const s16x8*)&hbuf[CUR_][lm][3 * 32 + lq * 8];                        \
        if (t_ + 2 < TSZ) xr = *(const float4*)(xrow + (size_t)(t_ + 2) * XROW);            \
        f32x4 hacc[4];                                                                      \
        _Pragma("unroll")                                                                   \
        for (int g = 0; g < 4; ++g)                                                         \
            hacc[g] = __builtin_amdgcn_mfma_f32_16x16x32_bf16(ah0, whh[g][0], xaccA[g], 0, 0, 0); \
        _Pragma("unroll")                                                                   \
        for (int g = 0; g < 4; ++g)                                                         \
            hacc[g] = __builtin_amdgcn_mfma_f32_16x16x32_bf16(ah1, whh[g][1], hacc[g], 0, 0, 0); \
        _Pragma("unroll")                                                                   \
        for (int g = 0; g < 4; ++g)                                                         \
            hacc[g] = __builtin_amdgcn_mfma_f32_16x16x32_bf16(ah2, whh[g][2], hacc[g], 0, 0, 0); \
        _Pragma("unroll")                                                                   \
        for (int g = 0; g < 4; ++g)                                                         \
            hacc[g] = __builtin_amdgcn_mfma_f32_16x16x32_bf16(ah3, whh[g][3], hacc[g], 0, 0, 0); \
        if (t_ + 1 < TSZ) {                                                                 \
            _Pragma("unroll")                                                               \
            for (int kt = 0; kt < 4; ++kt) {                                                \
                s16x8 axk = *(const s16x8*)&xbuf[NXT_][lm][kt * 32 + lq * 8];               \
                _Pragma("unroll")                                                           \
                for (int g = 0; g < 4; ++g)                                                 \
                    xaccA[g] = __builtin_amdgcn_mfma_f32_16x16x32_bf16(                     \
                        axk, wih[g][kt], kt == 0 ? biasv[g] : xaccA[g], 0, 0, 0);           \
            }                                                                               \
        }                                                                                   \
        PH_EPI(NXT_);                                                                       \
    }

        for (int t = 0; t < TSZ; t += 2) {
            STEP_0(t, 0, 1);
            STEP_0(t + 1, 1, 0);
        }
#undef STEP_0
    }
#undef PH_EPI

    // finals: h_n, c_n  [1, B, N*H] each
    const size_t hn_off = (size_t)BSZ * TSZ * OROW;
    const size_t cn_off = hn_off + (size_t)BSZ * OROW;
    #pragma unroll
    for (int r = 0; r < 4; ++r) {
        const int row = lq * 4 + r;
        const size_t idx = (size_t)(b0 + row) * OROW + ocol;
        out[hn_off + idx] = hlast[r];
        out[cn_off + idx] = cprev[r];
    }
}

extern "C" void kernel_launch(void* const* d_in, const int* in_sizes, int n_in,
                              void* d_out, int out_size, void* d_ws, size_t ws_size,
                              hipStream_t stream) {
    const float* x   = (const float*)d_in[0];
    const float* Wih = (const float*)d_in[1];
    const float* Whh = (const float*)d_in[2];
    const float* bih = (const float*)d_in[3];
    const float* bhh = (const float*)d_in[4];
    float* out = (float*)d_out;

    const size_t needFR = (size_t)TSZ * 32 * 4 * 64 * 16;   // 64 MiB
    if (d_ws != nullptr && ws_size >= needFR) {
        int4* xfrag = (int4*)d_ws;
        x_to_frag<<<dim3(16384), dim3(256), 0, stream>>>(x, xfrag);
        widelstm_fused<1><<<dim3(32), dim3(512), 0, stream>>>(x, xfrag, Wih, Whh, bih, bhh, out);
    } else {
        widelstm_fused<0><<<dim3(32), dim3(512), 0, stream>>>(x, nullptr, Wih, Whh, bih, bhh, out);
    }
}